// Round 6
// baseline (52.736 us; speedup 1.0000x reference)
//
#include <hip/hip_runtime.h>
#include <math.h>

// Problem constants (reference: B=128, S=2048, D=128)
#define BB 128
#define SS 2048
#define DD 128
#define BS (BB * SS)              // 262144 rows per half
#define GBLOCKS 8192              // gather: 8192 blocks * 8 groups = 65536 base rows
#define RSTRIDE (GBLOCKS * 8)     // 65536 row stride for the it-loop

typedef float f4 __attribute__((ext_vector_type(4)));

// ---------------------------------------------------------------------------
// Kernel A (prep): invert both permutations.
//   vt[half][b][ perm[b*S+i] ] = i    (random 4B writes into 2MiB, L2-merged)
// ---------------------------------------------------------------------------
__global__ __launch_bounds__(256) void invert_kernel(
        const int* __restrict__ sol, const int* __restrict__ best,
        int* __restrict__ vt) {
    const int idx = blockIdx.x * 256 + threadIdx.x;    // [0, 2*BS)
    const int half = (idx >= BS) ? 1 : 0;
    const int k    = half ? idx - BS : idx;            // b*S + i
    const int i    = k & (SS - 1);
    const int node = half ? best[k] : sol[k];
    vt[half * BS + (k - i) + node] = i;                // visited_time[b][node]=i
}

// ---------------------------------------------------------------------------
// Kernel B (gather): out[r][:] = pe[vt[r]][:] with SEQUENTIAL output writes
// and pe computed on the fly (no table, no heavy random access anywhere).
// 32 lanes per row; lane handles j = 4*lane..4*lane+3.
//   invf_p = 10000^(-p/64)  (p = j>>1, loop-invariant per lane)
//   angle  = (i+1)*invf ;  sin/cos via revolution-reduced v_sin/v_cos
// Row i==0 keeps the raw angle (reference quirk).
// ---------------------------------------------------------------------------
__global__ __launch_bounds__(256) void gather_trig_kernel(
        const int* __restrict__ vt, float* __restrict__ out) {
    const int t    = threadIdx.x;
    const int lane = t & 31;
    const int rib  = t >> 5;
    const int base = blockIdx.x * 8 + rib;             // [0, 65536)

    // per-lane constants
    const float c = -13.287712379549449f / 64.0f;      // -log2(10000)/64
    const float invf0 = exp2f(c * (float)(2 * lane));
    const float invf1 = exp2f(c * (float)(2 * lane + 1));
    const float INV2PI = 0.15915494309189535f;

    // issue all 8 index loads up front (independent, broadcast per group)
    int iv[8];
    #pragma unroll
    for (int it = 0; it < 8; ++it)
        iv[it] = vt[base + it * RSTRIDE];

    #pragma unroll
    for (int it = 0; it < 8; ++it) {
        const int i = iv[it];
        const float a0 = (float)(i + 1) * invf0;
        const float a1 = (float)(i + 1) * invf1;
        f4 v;
        if (i == 0) {
            v[0] = a0; v[1] = a0; v[2] = a1; v[3] = a1;
        } else {
            float f0 = a0 * INV2PI; f0 -= floorf(f0);   // revolutions in [0,1)
            float f1 = a1 * INV2PI; f1 -= floorf(f1);
            v[0] = __builtin_amdgcn_sinf(f0);
            v[1] = __builtin_amdgcn_cosf(f0);
            v[2] = __builtin_amdgcn_sinf(f1);
            v[3] = __builtin_amdgcn_cosf(f1);
        }
        const int r = base + it * RSTRIDE;              // sequential output row
        ((f4*)(out + (size_t)r * DD))[lane] = v;
    }
}

// ---------------------------------------------------------------------------
// Fallback (ws too small): R5's fused scatter (46.0 us) — known good.
// ---------------------------------------------------------------------------
__global__ __launch_bounds__(256) void fused_scatter_kernel(
        const int* __restrict__ sol, const int* __restrict__ best,
        float* __restrict__ out) {
    const int t    = threadIdx.x;
    const int lane = t & 31;
    const int rib  = t >> 5;
    const int base = blockIdx.x * 8 + rib;
    const int i    = base & (SS - 1);

    const float c = -13.287712379549449f / 64.0f;
    const float invf0 = exp2f(c * (float)(2 * lane));
    const float invf1 = exp2f(c * (float)(2 * lane + 1));
    const float a0 = (float)(i + 1) * invf0;
    const float a1 = (float)(i + 1) * invf1;
    f4 v;
    if (i == 0) {
        v[0] = a0; v[1] = a0; v[2] = a1; v[3] = a1;
    } else {
        float s0, c0, s1, c1;
        sincosf(a0, &s0, &c0);
        sincosf(a1, &s1, &c1);
        v[0] = s0; v[1] = c0; v[2] = s1; v[3] = c1;
    }
    #pragma unroll
    for (int h = 0; h < 2; ++h) {
        const int* __restrict__ perm = h ? best : sol;
        float* __restrict__ outh = out + (size_t)h * BS * DD;
        #pragma unroll
        for (int it = 0; it < 4; ++it) {
            const int k    = base + it * RSTRIDE;
            const int node = perm[k];
            const int dstRow = (k - i) + node;
            ((f4*)(outh + (size_t)dstRow * DD))[lane] = v;
        }
    }
}

extern "C" void kernel_launch(void* const* d_in, const int* in_sizes, int n_in,
                              void* d_out, int out_size, void* d_ws, size_t ws_size,
                              hipStream_t stream) {
    // inputs: d_in[0] = x (f32, unused), d_in[1] = solutions, d_in[2] = best_solutions
    const int* sol  = (const int*)d_in[1];
    const int* best = (const int*)d_in[2];
    float* out = (float*)d_out;

    const size_t vtBytes = (size_t)2 * BS * sizeof(int);   // 2 MiB

    if (ws_size >= vtBytes) {
        int* vt = (int*)d_ws;
        invert_kernel<<<(2 * BS) / 256, 256, 0, stream>>>(sol, best, vt);
        gather_trig_kernel<<<GBLOCKS, 256, 0, stream>>>(vt, out);
    } else {
        fused_scatter_kernel<<<GBLOCKS, 256, 0, stream>>>(sol, best, out);
    }
    (void)in_sizes; (void)n_in; (void)out_size;
}

// Round 7
// 46.024 us; speedup vs baseline: 1.1458x; 1.1458x over previous
//
#include <hip/hip_runtime.h>
#include <math.h>

// Problem constants (reference: B=128, S=2048, D=128)
#define BB 128
#define SS 2048
#define DD 128
#define BS (BB * SS)              // 262144 rows per half
#define BLOCKS 4096               // 4096 blocks * 8 groups = 32768 base rows
#define RSTRIDE (BLOCKS * 8)      // 32768; 32768 % 2048 == 0 -> i invariant
#define ITERS 8                   // 8 strided rows per half -> 16 stores/thread

typedef float f4 __attribute__((ext_vector_type(4)));

// ---------------------------------------------------------------------------
// Single fused kernel, 16 rows per 32-lane group.
// base = blockIdx*8 + rib in [0, 32768); rows base + it*32768, it=0..7,
// for both halves. i = base & 2047 is invariant across all 16 rows, so each
// thread computes its 4 pe values ONCE (2 sincos pairs), then issues 16
// independent scattered 512B row writes (16 uniform index loads up front).
//   out[half][b][node][:] = pe[i][:],  node = perm[half][b*S + i]
// ---------------------------------------------------------------------------
__global__ __launch_bounds__(256) void fused_scatter_kernel(
        const int* __restrict__ sol, const int* __restrict__ best,
        float* __restrict__ out) {
    const int t    = threadIdx.x;
    const int lane = t & 31;            // 32 lanes/row, f4 each = 512 B
    const int rib  = t >> 5;            // 8 row-groups per 256-thread block
    const int base = blockIdx.x * 8 + rib;   // [0, 32768)
    const int i    = base & (SS - 1);        // pe row, invariant

    // issue all 16 index loads first (independent, uniform per group)
    int node[2][ITERS];
    #pragma unroll
    for (int it = 0; it < ITERS; ++it) {
        const int k = base + it * RSTRIDE;
        node[0][it] = sol[k];
        node[1][it] = best[k];
    }

    // pe values for j = 4*lane + {0,1,2,3}:  invf = 10000^(-(j>>1)/64)
    const float c = -13.287712379549449f / 64.0f;   // -log2(10000)/64
    const float invf0 = exp2f(c * (float)(2 * lane));
    const float invf1 = exp2f(c * (float)(2 * lane + 1));
    const float a0 = (float)(i + 1) * invf0;
    const float a1 = (float)(i + 1) * invf1;
    f4 v;
    if (i == 0) {               // reference quirk: row 0 stays raw angle
        v[0] = a0; v[1] = a0; v[2] = a1; v[3] = a1;
    } else {
        float s0, c0, s1, c1;
        sincosf(a0, &s0, &c0);
        sincosf(a1, &s1, &c1);
        v[0] = s0; v[1] = c0; v[2] = s1; v[3] = c1;
    }

    // 16 scattered row writes (2 halves x 8 strided rows)
    #pragma unroll
    for (int h = 0; h < 2; ++h) {
        float* __restrict__ outh = out + (size_t)h * BS * DD;
        #pragma unroll
        for (int it = 0; it < ITERS; ++it) {
            const int k      = base + it * RSTRIDE;   // b*S + i
            const int dstRow = (k - i) + node[h][it]; // b*S + node
            ((f4*)(outh + (size_t)dstRow * DD))[lane] = v;
        }
    }
}

extern "C" void kernel_launch(void* const* d_in, const int* in_sizes, int n_in,
                              void* d_out, int out_size, void* d_ws, size_t ws_size,
                              hipStream_t stream) {
    // inputs: d_in[0] = x (f32, unused), d_in[1] = solutions, d_in[2] = best_solutions
    const int* sol  = (const int*)d_in[1];
    const int* best = (const int*)d_in[2];
    float* out = (float*)d_out;

    fused_scatter_kernel<<<BLOCKS, 256, 0, stream>>>(sol, best, out);

    (void)in_sizes; (void)n_in; (void)out_size; (void)d_ws; (void)ws_size;
}